// Round 1
// 255.234 us; speedup vs baseline: 1.0198x; 1.0198x over previous
//
#include <hip/hip_runtime.h>

#define HH 1024
#define WW 1024
#define ROWS 16            // rows per thread; grid.y = HH/ROWS
#define EPSF 1e-8f

typedef float vfloat4 __attribute__((ext_vector_type(4)));

__device__ __forceinline__ float rcpf(float x) { return __builtin_amdgcn_rcpf(x); }
__device__ __forceinline__ void ntstore4(float* p, float a, float b, float c, float d) {
    vfloat4 v = {a, b, c, d};
    __builtin_nontemporal_store(v, reinterpret_cast<vfloat4*>(p));
}

__global__ __launch_bounds__(256, 4) void demosaick(
    const float* __restrict__ mos,
    const float* __restrict__ gfilt,
    const float* __restrict__ gradf,
    float* __restrict__ out)
{
    const int tid = threadIdx.x;
    const int x0  = tid * 4;                  // 256 threads x 4 cols = full 1024-wide row band
    const int by = blockIdx.y, bz = blockIdx.z;
    const int ry0 = by * ROWS;
    const size_t plane = (size_t)HH * WW;
    const float* __restrict__ src = mos + (size_t)bz * plane;

    const float gf0 = gfilt[0], gf1 = gfilt[1], gf2 = gfilt[2];
    const float df0 = gradf[0], df1 = gradf[1], df2 = gradf[2];

    const bool eL = (x0 == 0);
    const bool eR = (x0 == WW - 4);
    const int bLc = eL ? 0 : x0 - 2;          // clamped, 8B-aligned
    const int bRc = eR ? WW - 2 : x0 + 4;

    // Window w[0..7] = m[yy, x0-2 .. x0+5], edge-replicated in x (pad=1 semantics).
    // yy must already be a valid row index.
    auto load_win = [&](int yy, float* w) {
        const float* row = src + (size_t)yy * WW;
        float4 q1 = *reinterpret_cast<const float4*>(row + x0);
        float2 q0 = *reinterpret_cast<const float2*>(row + bLc);
        float2 q2 = *reinterpret_cast<const float2*>(row + bRc);
        w[2] = q1.x; w[3] = q1.y; w[4] = q1.z; w[5] = q1.w;
        w[0] = eL ? q1.x : q0.x;
        w[1] = eL ? q1.x : q0.y;
        w[6] = eR ? q2.y : q2.x;
        w[7] = q2.y;
    };
    auto load_mrow = [&](int y, float* w) {   // full y edge-clamp (prologue only)
        load_win(min(max(y, 0), HH - 1), w);
    };

    auto gi_at = [&](const float* up, const float* mid, const float* dn, int j) -> float {
        float xl = mid[j - 1], xc = mid[j], xr = mid[j + 1];
        float yu = up[j], yd = dn[j];
        float dx = df0 * xl + df1 * xc + df2 * xr;
        float dy = df0 * yu + df1 * xc + df2 * yd;
        float gh = gf0 * xl + gf1 * xc + gf2 * xr;
        float gv = gf0 * yu + gf1 * xc + gf2 * yd;
        float adx = fabsf(dx), ady = fabsf(dy);
        float w = ady * rcpf(adx + ady + EPSF);
        return w * gh + (1.0f - w) * gv;
    };
    // G[g] <-> col x0-1+g (g=0..5); window idx j = g+1.
    auto green_row = [&](int y, const float* up, const float* mid, const float* dn, float* G) {
        if (y & 1) {
            G[0] = mid[1]; G[2] = mid[3]; G[4] = mid[5];
            G[1] = gi_at(up, mid, dn, 2);
            G[3] = gi_at(up, mid, dn, 4);
            G[5] = gi_at(up, mid, dn, 6);
        } else {
            G[1] = mid[2]; G[3] = mid[4]; G[5] = mid[6];
            G[0] = gi_at(up, mid, dn, 1);
            G[2] = gi_at(up, mid, dn, 3);
            G[4] = gi_at(up, mid, dn, 5);
        }
    };

    // Rolling 3-row window + 2-deep prefetch queue. P0/P1 hold rows y+2, y+3:
    // each loop step consumes a row that was LOADED TWO STEPS EARLIER, then
    // immediately re-issues its slot for row y+4 — >=2 row-loads in flight per
    // wave at all times, decoupling HBM latency from the compute chain.
    float A8[8], Mm1[8], M0[8], Mp1[8], P0[8], P1[8];
    float Gm1[6], G0[6], Gp1[6];
    load_mrow(ry0 - 2, A8);
    load_mrow(ry0 - 1, Mm1);
    load_mrow(ry0,     M0);
    load_mrow(ry0 + 1, Mp1);
    load_mrow(ry0 + 2, P0);
    load_mrow(ry0 + 3, P1);
    green_row(ry0 - 1, A8, Mm1, M0, Gm1);
    green_row(ry0,     Mm1, M0, Mp1, G0);

    const float wl0 = eL ? 0.0f : 1.0f;       // col x0-1 in image? (only p=0 can fail)
    const float wr3 = eR ? 0.0f : 1.0f;       // col x0+4 in image? (only p=3 can fail)
    // Loop-invariant reciprocals. Interior denominators are exactly 1.0f in fp32
    // (1.0+1e-8 and 0.5+1e-8 both round to the unperturbed value), so these are
    // 0.5/0.25 for interior lanes and 1.0/0.5 for the two edge lanes.
    const float invL = rcpf(0.5f * (wl0 + 1.0f) + EPSF);
    const float invR = rcpf(0.5f * (1.0f + wr3) + EPSF);
    const float halfL = 0.5f * invL, quarterL = 0.25f * invL;
    const float halfR = 0.5f * invR, quarterR = 0.25f * invR;

    float* __restrict__ obase = out + (size_t)bz * 3 * plane + (size_t)x0;
    float* prow = obase + (size_t)ry0 * WW;

    // One output row: green of y+1 from (M0,Mp1,Puse), chroma+store of row y,
    // shift windows, then (optionally) prefetch row y+4 into the freed slot.
    auto step = [&](int y, float* Puse, bool pf) {
        green_row(y + 1, M0, Mp1, Puse, Gp1);

        const float g0 = G0[1], g1 = G0[2], g2 = G0[3], g3 = G0[4];
        float R[4], Bv[4];

        if (__builtin_expect(y > 0 && y < HH - 1, 1)) {
            // -------- interior rows: all vertical/corner dens == 1 exactly --------
            if ((y & 1) == 0) {
                float dU0 = Mm1[2] - Gm1[1], dD0 = Mp1[2] - Gp1[1];
                float dU2 = Mm1[4] - Gm1[3], dD2 = Mp1[4] - Gp1[3];
                R[0]  = g0 + halfL * (wl0 * (M0[1] - G0[0]) + (M0[3] - G0[2]));
                Bv[0] = g0 + 0.5f * (dU0 + dD0);
                R[1]  = M0[3];
                Bv[1] = g1 + 0.25f * (dU0 + dU2 + dD0 + dD2);
                R[2]  = g2 + 0.5f * ((M0[3] - G0[2]) + (M0[5] - G0[4]));
                Bv[2] = g2 + 0.5f * (dU2 + dD2);
                R[3]  = M0[5];
                Bv[3] = g3 + quarterR * ((dU2 + dD2) + wr3 * ((Mm1[6] - Gm1[5]) + (Mp1[6] - Gp1[5])));
            } else {
                float dU1 = Mm1[3] - Gm1[2], dD1 = Mp1[3] - Gp1[2];
                float dU3 = Mm1[5] - Gm1[4], dD3 = Mp1[5] - Gp1[4];
                Bv[0] = M0[2];
                R[0]  = g0 + quarterL * (wl0 * ((Mm1[1] - Gm1[0]) + (Mp1[1] - Gp1[0])) + (dU1 + dD1));
                R[1]  = g1 + 0.5f * (dU1 + dD1);
                Bv[1] = g1 + 0.5f * ((M0[2] - G0[1]) + (M0[4] - G0[3]));
                Bv[2] = M0[4];
                R[2]  = g2 + 0.25f * (dU1 + dU3 + dD1 + dD3);
                R[3]  = g3 + 0.5f * (dU3 + dD3);
                Bv[3] = g3 + halfR * ((M0[4] - G0[3]) + wr3 * (M0[6] - G0[5]));
            }
        } else {
            // -------- border rows y==0 / y==HH-1: general masked path --------
            const float fU = (y > 0) ? 1.0f : 0.0f;
            const float fD = (y < HH - 1) ? 1.0f : 0.0f;
            auto wl = [&](int p) -> float { return p == 0 ? wl0 : 1.0f; };
            auto wr = [&](int p) -> float { return p == 3 ? wr3 : 1.0f; };
            auto pair_h = [&](int p) -> float {
                float dL = M0[p + 1] - G0[p], dR = M0[p + 3] - G0[p + 2];
                return G0[p + 1] + (0.5f * (wl(p) * dL + wr(p) * dR)) * rcpf(0.5f * (wl(p) + wr(p)) + EPSF);
            };
            auto pair_v = [&](int p) -> float {
                float dU = Mm1[p + 2] - Gm1[p + 1], dD = Mp1[p + 2] - Gp1[p + 1];
                return G0[p + 1] + (0.5f * (fU * dU + fD * dD)) * rcpf(0.5f * (fU + fD) + EPSF);
            };
            auto corners = [&](int p) -> float {
                float dUL = Mm1[p + 1] - Gm1[p],     dUR = Mm1[p + 3] - Gm1[p + 2];
                float dDL = Mp1[p + 1] - Gp1[p],     dDR = Mp1[p + 3] - Gp1[p + 2];
                float num = 0.25f * (fU * (wl(p) * dUL + wr(p) * dUR) + fD * (wl(p) * dDL + wr(p) * dDR));
                float den = 0.25f * ((fU + fD) * (wl(p) + wr(p)));
                return G0[p + 1] + num * rcpf(den + EPSF);
            };
            if ((y & 1) == 0) {
                R[0] = pair_h(0);  Bv[0] = pair_v(0);
                R[1] = M0[3];      Bv[1] = corners(1);
                R[2] = pair_h(2);  Bv[2] = pair_v(2);
                R[3] = M0[5];      Bv[3] = corners(3);
            } else {
                R[0] = corners(0); Bv[0] = M0[2];
                R[1] = pair_v(1);  Bv[1] = pair_h(1);
                R[2] = corners(2); Bv[2] = M0[4];
                R[3] = pair_v(3);  Bv[3] = pair_h(3);
            }
        }

        ntstore4(prow,             R[0], R[1], R[2], R[3]);
        ntstore4(prow + plane,     g0, g1, g2, g3);
        ntstore4(prow + 2 * plane, Bv[0], Bv[1], Bv[2], Bv[3]);
        prow += WW;

        #pragma unroll
        for (int j = 0; j < 8; ++j) { Mm1[j] = M0[j]; M0[j] = Mp1[j]; Mp1[j] = Puse[j]; }
        #pragma unroll
        for (int j = 0; j < 6; ++j) { Gm1[j] = G0[j]; G0[j] = Gp1[j]; }

        if (pf) {
            // In-loop prefetch: y+4 >= 4, only upper clamp needed (last band).
            load_win(min(y + 4, HH - 1), Puse);
        }
    };

    #pragma unroll 2
    for (int rr = 0; rr < ROWS - 2; rr += 2) {
        step(ry0 + rr,     P0, true);
        step(ry0 + rr + 1, P1, true);
    }
    // Peeled tail: no prefetch (rows would be wasted reads past the band).
    step(ry0 + ROWS - 2, P0, false);
    step(ry0 + ROWS - 1, P1, false);
}

extern "C" void kernel_launch(void* const* d_in, const int* in_sizes, int n_in,
                              void* d_out, int out_size, void* d_ws, size_t ws_size,
                              hipStream_t stream) {
    const float* mos = (const float*)d_in[0];
    const float* gf  = (const float*)d_in[1];
    const float* df  = (const float*)d_in[2];
    float* o = (float*)d_out;
    int B = in_sizes[0] / (HH * WW);
    dim3 grid(1, HH / ROWS, B);
    demosaick<<<grid, dim3(256, 1, 1), 0, stream>>>(mos, gf, df, o);
}